// Round 12
// baseline (324.505 us; speedup 1.0000x reference)
//
#include <hip/hip_runtime.h>
#include <hip/hip_bf16.h>

// ---------- constants ----------
#define NPATCH 76832   // 32 * 49 * 49
#define NBLK   601     // ceil(NPATCH/128)
#define K1     1280    // 20*8*8

typedef __attribute__((ext_vector_type(8))) short  short8;
typedef __attribute__((ext_vector_type(4))) float  floatx4;

__device__ __forceinline__ unsigned short f2b(float f) {
    unsigned int u = __builtin_bit_cast(unsigned int, f);
    u += 0x7FFFu + ((u >> 16) & 1u);   // RNE
    return (unsigned short)(u >> 16);
}
// HW packed f32x2 -> bf16x2 (v_cvt_pk_bf16_f32), a -> low
__device__ __forceinline__ unsigned int pk2(float a, float b) {
    __hip_bfloat162 h = __float22bfloat162_rn(make_float2(a, b));
    unsigned int u;
    __builtin_memcpy(&u, &h, 4);
    return u;
}

// async global->LDS, 16B/lane; global addr PER-LANE, lds dest = wave-uniform base + lane*16
__device__ __forceinline__ void gload_lds16(const unsigned short* g, unsigned short* l) {
    __builtin_amdgcn_global_load_lds(
        (__attribute__((address_space(1))) void*)g,
        (__attribute__((address_space(3))) void*)l,
        16, 0, 0);
}

// swizzled chunk index within a 128B pixel-pair window (conv layout)
__device__ __host__ __forceinline__ int swz8(int row, int i) {
    return (((row & 1) * 4 + i) ^ ((row >> 1) & 7));
}

// ---------- prep: weights into MFMA-fragment-coalesced layouts ----------
// F-layout for W[N][K]: element (o,k) -> (khg*16 + wave*4 + mt)*512 + lane*8 + j
//   wave=o>>6, mt=(o>>4)&3, l15=o&15, khg=k>>5, quad=(k>>3)&3, j=k&7, lane=quad*16+l15
// sections: W1F(327680) W2F(65536) W3F(65536) W1T(1024) W2T(9216) WfF(8192)
__global__ void prep(const float* __restrict__ f1w, const float* __restrict__ f2w,
                     const float* __restrict__ f3w, const float* __restrict__ c1w,
                     const float* __restrict__ c2w, const float* __restrict__ ffw,
                     unsigned short* __restrict__ W1F, unsigned short* __restrict__ W2F,
                     unsigned short* __restrict__ W3F, unsigned short* __restrict__ W1T,
                     unsigned short* __restrict__ W2T, unsigned short* __restrict__ WfF) {
    int i = blockIdx.x * 256 + threadIdx.x;
    if (i < 327680) {          // W1F: o in [0,256), k in [0,1280)
        int o = i / 1280, k = i - o * 1280;
        int dst = ((k >> 5) * 16 + (o >> 6) * 4 + ((o >> 4) & 3)) * 512
                + (((k >> 3) & 3) * 16 + (o & 15)) * 8 + (k & 7);
        W1F[dst] = f2b(f1w[i]);
        return;
    }
    i -= 327680;
    if (i < 65536) {           // W2F: o in [0,256), k in [0,256)
        int o = i >> 8, k = i & 255;
        int dst = ((k >> 5) * 16 + (o >> 6) * 4 + ((o >> 4) & 3)) * 512
                + (((k >> 3) & 3) * 16 + (o & 15)) * 8 + (k & 7);
        W2F[dst] = f2b(f2w[i]);
        return;
    }
    i -= 65536;
    if (i < 65536) {           // W3F
        int o = i >> 8, k = i & 255;
        int dst = ((k >> 5) * 16 + (o >> 6) * 4 + ((o >> 4) & 3)) * 512
                + (((k >> 3) & 3) * 16 + (o & 15)) * 8 + (k & 7);
        W3F[dst] = f2b(f3w[i]);
        return;
    }
    i -= 65536;
    if (i < 1024) {            // W1T[o:32][k:32], conv swizzle
        int o = i >> 5, k = i & 31;
        unsigned short v = 0;
        if (o < 20 && k < 18) v = f2b(c1w[o * 18 + k]);
        W1T[(o >> 1) * 64 + swz8(o, k >> 3) * 8 + (k & 7)] = v;
        return;
    }
    i -= 1024;
    if (i < 9216) {            // W2T[tap][o:32][c:32], conv swizzle
        int tap = i >> 10, rem = i & 1023, o = rem >> 5, c = rem & 31;
        unsigned short v = 0;
        if (o < 20 && c < 20) v = f2b(c2w[o * 180 + c * 9 + tap]);
        W2T[tap * 1024 + (o >> 1) * 64 + swz8(o, c >> 3) * 8 + (c & 7)] = v;
        return;
    }
    i -= 9216;
    if (i < 8192) {            // WfF: o in [0,32) (zero-pad >=27), k in [0,256)
        int o = i >> 8, k = i & 255;
        unsigned short v = (o < 27) ? f2b(ffw[o * 256 + k]) : (unsigned short)0;
        int dst = ((k >> 5) * 2 + (o >> 4)) * 512
                + (((k >> 3) & 3) * 16 + (o & 15)) * 8 + (k & 7);
        WfF[dst] = v;
    }
}

// ---------- fused tile + conv1(MFMA) + conv2(MFMA) (R0/R6-proven, DO NOT EDIT) ----------
// R5/R9 lessons: this structure is load-bearing — conditional window loads,
// layout changes (2080 stride / 3-store pack), and conv2 inner restructure all
// regressed despite lower VALU work. Weight LDS staging is load-bearing (R7).
__global__ __launch_bounds__(256, 3) void conv_mfma(
    const float* __restrict__ img,
    const unsigned short* __restrict__ W1T, const float* __restrict__ b1,
    const unsigned short* __restrict__ W2T, const float* __restrict__ b2,
    unsigned short* __restrict__ X, int row0)
{
    __shared__ alignas(16) unsigned short s_buf[8 * 2048 + 64];
    __shared__ alignas(16) unsigned short s_w1t[1024];
    __shared__ alignas(16) unsigned short s_w2t[9216];
    __shared__ float s_b1[32], s_b2[32];
    constexpr int ZOFF = 8 * 2048;

    const int tid = threadIdx.x;
    for (int d = tid; d < 512; d += 256)  ((unsigned int*)s_w1t)[d] = ((const unsigned int*)W1T)[d];
    for (int d = tid; d < 4608; d += 256) ((unsigned int*)s_w2t)[d] = ((const unsigned int*)W2T)[d];
    if (tid < 32) {
        ((unsigned int*)&s_buf[ZOFF])[tid] = 0u;
        s_b1[tid] = (tid < 20) ? b1[tid] : 0.f;
        s_b2[tid] = (tid < 20) ? b2[tid] : 0.f;
    }

    const int q = tid >> 5, t = tid & 31;
    const int Pl = blockIdx.x * 8 + q;
    const int Pi = row0 + Pl;
    const bool valid = Pi < NPATCH;
    int b = 0, hi = 0, wi = 0;
    if (valid) { b = Pi / 2401; int rem = Pi - b * 2401; hi = rem / 49; wi = rem - hi * 49; }
    const int py = t >> 2, px0 = (t & 3) * 2;
    const float* ib = img + (long long)b * 21632 + (hi * 2) * 104 + (wi * 2);

    float win[2][3][4];
    #pragma unroll
    for (int c = 0; c < 2; ++c)
        #pragma unroll
        for (int dy = 0; dy < 3; ++dy) {
            int ny = py + dy - 1;
            int nyc = ny < 0 ? 0 : (ny > 7 ? 7 : ny);
            #pragma unroll
            for (int dxw = 0; dxw < 4; ++dxw) {
                int nx = px0 + dxw - 1;
                int nxc = nx < 0 ? 0 : (nx > 7 ? 7 : nx);
                win[c][dy][dxw] = ib[c * 10816 + nyc * 104 + nxc];
            }
        }

    #pragma unroll
    for (int j = 0; j < 2; ++j) {
        const int px = px0 + j, pl = py * 8 + px;
        float val[18];
        #pragma unroll
        for (int c = 0; c < 2; ++c)
            #pragma unroll
            for (int dy = 0; dy < 3; ++dy) {
                int ny = py + dy - 1;
                bool rok = valid && ((unsigned)ny < 8u);
                #pragma unroll
                for (int dx = 0; dx < 3; ++dx) {
                    int nx = px + dx - 1;
                    bool ok = rok && ((unsigned)nx < 8u);
                    val[c * 9 + dy * 3 + dx] = ok ? win[c][dy][dx + j] : 0.f;
                }
            }
        alignas(16) unsigned int au[16];
        #pragma unroll
        for (int i = 0; i < 9; ++i) au[i] = pk2(val[2 * i], val[2 * i + 1]);
        #pragma unroll
        for (int i = 9; i < 16; ++i) au[i] = 0u;
        unsigned short* base = &s_buf[q * 2048 + (pl >> 1) * 64];
        #pragma unroll
        for (int i = 0; i < 4; ++i)
            *(uint4*)&base[swz8(pl, i) * 8] = ((const uint4*)au)[i];
    }
    __syncthreads();

    const int wave = tid >> 6, lane = tid & 63;
    const int l15 = lane & 15, quad = lane >> 4;
    const int p0 = wave * 2;

    int boffB[2];
    #pragma unroll
    for (int i = 0; i < 2; ++i) {
        int oo = i * 16 + l15;
        boffB[i] = (oo >> 1) * 64 + swz8(oo, quad) * 8;
    }

    short8 a1f[2];
    #pragma unroll
    for (int mt = 0; mt < 2; ++mt) a1f[mt] = *(const short8*)&s_w1t[boffB[mt]];

    floatx4 acc1[2][2][4] = {};
    #pragma unroll
    for (int pp = 0; pp < 2; ++pp)
        #pragma unroll
        for (int nt = 0; nt < 4; ++nt) {
            int pix = nt * 16 + l15;
            short8 pf = *(const short8*)&s_buf[(p0 + pp) * 2048 + (pix >> 1) * 64 + swz8(pix, quad) * 8];
            #pragma unroll
            for (int mt = 0; mt < 2; ++mt)
                acc1[pp][mt][nt] = __builtin_amdgcn_mfma_f32_16x16x32_bf16(a1f[mt], pf, acc1[pp][mt][nt], 0, 0, 0);
        }

    float bv1[2][4];
    #pragma unroll
    for (int mt = 0; mt < 2; ++mt)
        #pragma unroll
        for (int r = 0; r < 4; ++r) bv1[mt][r] = s_b1[mt * 16 + quad * 4 + r];

    #pragma unroll
    for (int pp = 0; pp < 2; ++pp)
        #pragma unroll
        for (int mt = 0; mt < 2; ++mt)
            #pragma unroll
            for (int nt = 0; nt < 4; ++nt) {
                floatx4 v = acc1[pp][mt][nt];
                uint2 w;
                w.x = pk2(fmaxf(v[0] + bv1[mt][0], 0.f), fmaxf(v[1] + bv1[mt][1], 0.f));
                w.y = pk2(fmaxf(v[2] + bv1[mt][2], 0.f), fmaxf(v[3] + bv1[mt][3], 0.f));
                int pix = nt * 16 + l15;
                int off = (p0 + pp) * 2048 + (pix >> 1) * 64
                        + swz8(pix, mt * 2 + (quad >> 1)) * 8 + (quad & 1) * 4;
                *(uint2*)&s_buf[off] = w;
            }

    int syv[4], pxv[4];
    #pragma unroll
    for (int mt = 0; mt < 4; ++mt) { int p = mt * 16 + l15; syv[mt] = p >> 3; pxv[mt] = p & 7; }

    floatx4 acc2[2][4][2] = {};
    #pragma unroll 1
    for (int dy = 0; dy < 3; ++dy) {
        int sy[4]; bool okY[4];
        #pragma unroll
        for (int mt = 0; mt < 4; ++mt) {
            sy[mt] = syv[mt] + dy - 1;
            okY[mt] = (unsigned)sy[mt] < 8u;
        }
        #pragma unroll
        for (int dx = 0; dx < 3; ++dx) {
            const int tap = dy * 3 + dx;
            short8 bf0 = *(const short8*)&s_w2t[tap * 1024 + boffB[0]];
            short8 bf1 = *(const short8*)&s_w2t[tap * 1024 + boffB[1]];
            #pragma unroll
            for (int mt = 0; mt < 4; ++mt) {
                int sx = pxv[mt] + dx - 1;
                bool ok = okY[mt] & ((unsigned)sx < 8u);
                int ps = sy[mt] * 8 + sx;
                int offl = (ps >> 1) * 64 + swz8(ps, quad) * 8;
                #pragma unroll
                for (int pp = 0; pp < 2; ++pp) {
                    int off = ok ? ((p0 + pp) * 2048 + offl) : (ZOFF + quad * 8);
                    short8 af = *(const short8*)&s_buf[off];
                    acc2[pp][mt][0] = __builtin_amdgcn_mfma_f32_16x16x32_bf16(af, bf0, acc2[pp][mt][0], 0, 0, 0);
                    acc2[pp][mt][1] = __builtin_amdgcn_mfma_f32_16x16x32_bf16(af, bf1, acc2[pp][mt][1], 0, 0, 0);
                }
            }
        }
    }

    #pragma unroll
    for (int pp = 0; pp < 2; ++pp) {
        unsigned short* xrow = X + (long long)(blockIdx.x * 8 + p0 + pp) * K1;
        #pragma unroll
        for (int nt = 0; nt < 2; ++nt) {
            const int col = nt * 16 + l15;
            if (col < 20) {
                const float bv = s_b2[col];
                #pragma unroll
                for (int mt = 0; mt < 4; ++mt) {
                    floatx4 v = acc2[pp][mt][nt];
                    uint2 w;
                    w.x = pk2(fmaxf(v[0] + bv, 0.f), fmaxf(v[1] + bv, 0.f));
                    w.y = pk2(fmaxf(v[2] + bv, 0.f), fmaxf(v[3] + bv, 0.f));
                    *(uint2*)&xrow[col * 64 + mt * 16 + quad * 4] = w;
                }
            }
        }
    }
}

// ---------- fc_all v7 (R6-proven best, ~125 µs): BK=64, af-before-stage, setprio ----------
__global__ __launch_bounds__(256, 3) void fc_all(
    const unsigned short* __restrict__ X,
    const unsigned short* __restrict__ W1F, const unsigned short* __restrict__ W2F,
    const unsigned short* __restrict__ W3F, const unsigned short* __restrict__ WfF,
    const float* __restrict__ b1, const float* __restrict__ b2,
    const float* __restrict__ b3, const float* __restrict__ bf_,
    float* __restrict__ out, int row0)
{
    __shared__ alignas(16) unsigned short s_mem[16384];   // 32 KB

    const int tid = threadIdx.x;
    const int m0 = blockIdx.x * 64;
    const int wave = tid >> 6, lane = tid & 63;
    const int l15 = lane & 15, quad = lane >> 4;

    floatx4 acc[4][4];
    #pragma unroll
    for (int mt = 0; mt < 4; ++mt)
        #pragma unroll
        for (int nt = 0; nt < 4; ++nt) acc[mt][nt] = floatx4{0.f, 0.f, 0.f, 0.f};

    // ======== fc1: K=1280 = 40 khg; chunk = 2 khg (8KB LDS), double-buffered ========
    const unsigned short* xsrc = X + (long long)(m0 + wave * 16 + l15) * 1280 + quad * 8;
    auto stage = [&](int buf, int c) {
        unsigned short* dst = &s_mem[buf * 4096 + wave * 512];
        gload_lds16(xsrc + (2 * c) * 32, dst);            // block (0*4 + wave)
        gload_lds16(xsrc + (2 * c + 1) * 32, dst + 2048); // block (1*4 + wave)
    };

    stage(0, 0);
    __syncthreads();
    #pragma unroll 2
    for (int c = 0; c < 20; ++c) {
        // 1) ALL af fragments of chunk c first (32 VGPR)
        short8 af[2][4];
        #pragma unroll
        for (int kh = 0; kh < 2; ++kh)
            #pragma unroll
            for (int mt = 0; mt < 4; ++mt)
                af[kh][mt] = *(const short8*)(W1F + (((2 * c + kh) * 16) + wave * 4 + mt) * 512 + lane * 8);
        __builtin_amdgcn_sched_barrier(0);   // pin: af loads precede the prefetch
        // 2) prefetch next X chunk (stays in flight: af waits never drain it)
        if (c < 19) stage((c + 1) & 1, c + 1);
        // 3) compute
        const int bb = (c & 1) * 4096;
        __builtin_amdgcn_s_setprio(1);
        #pragma unroll
        for (int kh = 0; kh < 2; ++kh) {
            short8 bf[4];
            #pragma unroll
            for (int nt = 0; nt < 4; ++nt)
                bf[nt] = *(const short8*)&s_mem[bb + (kh * 4 + nt) * 512 + lane * 8];
            #pragma unroll
            for (int mt = 0; mt < 4; ++mt)
                #pragma unroll
                for (int nt = 0; nt < 4; ++nt)
                    acc[mt][nt] = __builtin_amdgcn_mfma_f32_16x16x32_bf16(af[kh][mt], bf[nt], acc[mt][nt], 0, 0, 0);
        }
        __builtin_amdgcn_s_setprio(0);
        __syncthreads();   // drains prefetch (vmcnt 0) AFTER the compute phase
    }

    // h1 = relu(acc + b1) -> s_mem in fragment order (k dim = fc1 output o)
    #pragma unroll
    for (int mt = 0; mt < 4; ++mt) {
        const int obase = wave * 64 + mt * 16 + quad * 4;
        const float v0 = b1[obase], v1 = b1[obase + 1], v2 = b1[obase + 2], v3 = b1[obase + 3];
        const int slot = (wave * 2 + (mt >> 1)) * 4;          // khg*4
        const int qk = (mt & 1) * 2 + (quad >> 1);
        #pragma unroll
        for (int nt = 0; nt < 4; ++nt) {
            floatx4 v = acc[mt][nt];
            uint2 w;
            w.x = pk2(fmaxf(v[0] + v0, 0.f), fmaxf(v[1] + v1, 0.f));
            w.y = pk2(fmaxf(v[2] + v2, 0.f), fmaxf(v[3] + v3, 0.f));
            *(uint2*)&s_mem[(slot + nt) * 512 + qk * 128 + l15 * 8 + (quad & 1) * 4] = w;
        }
    }
    __syncthreads();

    // ======== fc2 / fc3: A = W F-layout (global/L2), depth-1 af pipeline ========
    #pragma unroll 1
    for (int layer = 0; layer < 2; ++layer) {
        const unsigned short* Wp = (layer == 0) ? W2F : W3F;
        const float* bp = (layer == 0) ? b2 : b3;

        #pragma unroll
        for (int mt = 0; mt < 4; ++mt)
            #pragma unroll
            for (int nt = 0; nt < 4; ++nt) acc[mt][nt] = floatx4{0.f, 0.f, 0.f, 0.f};

        short8 afc[4];
        #pragma unroll
        for (int mt = 0; mt < 4; ++mt)
            afc[mt] = *(const short8*)(Wp + (wave * 4 + mt) * 512 + lane * 8);

        #pragma unroll
        for (int it = 0; it < 8; ++it) {
            short8 afn[4];
            if (it < 7) {
                #pragma unroll
                for (int mt = 0; mt < 4; ++mt)
                    afn[mt] = *(const short8*)(Wp + ((it + 1) * 16 + wave * 4 + mt) * 512 + lane * 8);
            }
            short8 bf[4];
            #pragma unroll
            for (int nt = 0; nt < 4; ++nt)
                bf[nt] = *(const short8*)&s_mem[(it * 4 + nt) * 512 + lane * 8];
            __builtin_amdgcn_s_setprio(1);
            #pragma unroll
            for (int mt = 0; mt < 4; ++mt)
                #pragma unroll
                for (int nt = 0; nt < 4; ++nt)
                    acc[mt][nt] = __builtin_amdgcn_mfma_f32_16x16x32_bf16(afc[mt], bf[nt], acc[mt][nt], 0, 0, 0);
            __builtin_amdgcn_s_setprio(0);
            if (it < 7) {
                #pragma unroll
                for (int mt = 0; mt < 4; ++mt) afc[mt] = afn[mt];
            }
        }
        __syncthreads();   // all reads of h done before overwrite
        #pragma unroll
        for (int mt = 0; mt < 4; ++mt) {
            const int obase = wave * 64 + mt * 16 + quad * 4;
            const float v0 = bp[obase], v1 = bp[obase + 1], v2 = bp[obase + 2], v3 = bp[obase + 3];
            const int slot = (wave * 2 + (mt >> 1)) * 4;
            const int qk = (mt & 1) * 2 + (quad >> 1);
            #pragma unroll
            for (int nt = 0; nt < 4; ++nt) {
                floatx4 v = acc[mt][nt];
                uint2 w;
                w.x = pk2(fmaxf(v[0] + v0, 0.f), fmaxf(v[1] + v1, 0.f));
                w.y = pk2(fmaxf(v[2] + v2, 0.f), fmaxf(v[3] + v3, 0.f));
                *(uint2*)&s_mem[(slot + nt) * 512 + qk * 128 + l15 * 8 + (quad & 1) * 4] = w;
            }
        }
        __syncthreads();
    }

    // ======== fcf: A = WfF (global, coalesced), B = h3 fragments ========
    floatx4 accf[2] = {floatx4{0.f, 0.f, 0.f, 0.f}, floatx4{0.f, 0.f, 0.f, 0.f}};
    const int myrow = wave * 16 + l15;
    #pragma unroll
    for (int w8 = 0; w8 < 8; ++w8) {
        short8 bfr = *(const short8*)&s_mem[(w8 * 4 + wave) * 512 + lane * 8];
        #pragma unroll
        for (int mt = 0; mt < 2; ++mt) {
            short8 afr = *(const short8*)(WfF + (w8 * 2 + mt) * 512 + lane * 8);
            accf[mt] = __builtin_amdgcn_mfma_f32_16x16x32_bf16(afr, bfr, accf[mt], 0, 0, 0);
        }
    }
    const int grow = row0 + m0 + myrow;
    if (grow < NPATCH) {
        #pragma unroll
        for (int mt = 0; mt < 2; ++mt) {
            #pragma unroll
            for (int r = 0; r < 4; ++r) {
                int o = mt * 16 + quad * 4 + r;
                if (o < 27)
                    out[(long long)grow * 27 + o] = accf[mt][r] + bf_[o];
            }
        }
    }
}

extern "C" void kernel_launch(void* const* d_in, const int* in_sizes, int n_in,
                              void* d_out, int out_size, void* d_ws, size_t ws_size,
                              hipStream_t stream) {
    const float* images = (const float*)d_in[0];
    const float* c1w = (const float*)d_in[1];
    const float* c1b = (const float*)d_in[2];
    const float* c2w = (const float*)d_in[3];
    const float* c2b = (const float*)d_in[4];
    const float* f1w = (const float*)d_in[5];
    const float* f1b = (const float*)d_in[6];
    const float* f2w = (const float*)d_in[7];
    const float* f2b_ = (const float*)d_in[8];
    const float* f3w = (const float*)d_in[9];
    const float* f3b = (const float*)d_in[10];
    const float* ffw = (const float*)d_in[11];
    const float* ffb = (const float*)d_in[12];

    // ws: [W1F][W2F][W3F][W1T][W2T][WfF][X]
    const long long W1_E = 327680, W2_E = 65536, W3_E = 65536;
    const long long W1T_E = 1024, W2T_E = 9216, WF_E = 8192;
    const long long WB = (W1_E + W2_E + W3_E + W1T_E + W2T_E + WF_E) * 2;  // 954368
    char* ws = (char*)d_ws;
    unsigned short* W1F = (unsigned short*)ws;
    unsigned short* W2F = W1F + W1_E;
    unsigned short* W3F = W2F + W2_E;
    unsigned short* W1T = W3F + W3_E;
    unsigned short* W2T = W1T + W1T_E;
    unsigned short* WfF = W2T + W2T_E;
    unsigned short* X   = (unsigned short*)(ws + WB);

    // per 128-row block: X only = 327680 B
    long long avail = (long long)ws_size - WB - 256;
    int nb_max = (int)(avail / 327680LL);
    if (nb_max < 1) nb_max = 1;
    if (nb_max > NBLK) nb_max = NBLK;
    // Force >=2 chunks: per-chunk X (~98 MB) fits the 256 MB Infinity Cache, so
    // fc(i)'s X reads can hit L3 right after conv(i) wrote it; also makes fc_all
    // dispatches short enough to appear in the rocprof top-5 (fc counters).
    if (nb_max >= NBLK) nb_max = (NBLK + 1) / 2;   // 301
    int nchunks = (NBLK + nb_max - 1) / nb_max;
    int nb_even = (NBLK + nchunks - 1) / nchunks;

    prep<<<1864, 256, 0, stream>>>(f1w, f2w, f3w, c1w, c2w, ffw, W1F, W2F, W3F, W1T, W2T, WfF);

    for (int b0 = 0; b0 < NBLK; b0 += nb_even) {
        int nb = NBLK - b0; if (nb > nb_even) nb = nb_even;
        int row0 = b0 * 128;
        int rows = nb * 128;

        conv_mfma<<<rows / 8, 256, 0, stream>>>(images, W1T, c1b, W2T, c2b, X, row0);
        fc_all<<<rows / 64, 256, 0, stream>>>(X, W1F, W2F, W3F, WfF,
                                              f1b, f2b_, f3b, ffb, (float*)d_out, row0);
    }
}

// Round 13
// 304.113 us; speedup vs baseline: 1.0671x; 1.0671x over previous
//
#include <hip/hip_runtime.h>
#include <hip/hip_bf16.h>

// ---------- constants ----------
#define NPATCH 76832   // 32 * 49 * 49
#define NBLK   601     // ceil(NPATCH/128)
#define K1     1280    // 20*8*8

typedef __attribute__((ext_vector_type(8))) short  short8;
typedef __attribute__((ext_vector_type(4))) float  floatx4;

__device__ __forceinline__ unsigned short f2b(float f) {
    unsigned int u = __builtin_bit_cast(unsigned int, f);
    u += 0x7FFFu + ((u >> 16) & 1u);   // RNE
    return (unsigned short)(u >> 16);
}
// HW packed f32x2 -> bf16x2 (v_cvt_pk_bf16_f32), a -> low
__device__ __forceinline__ unsigned int pk2(float a, float b) {
    __hip_bfloat162 h = __float22bfloat162_rn(make_float2(a, b));
    unsigned int u;
    __builtin_memcpy(&u, &h, 4);
    return u;
}

// async global->LDS, 16B/lane; global addr PER-LANE, lds dest = wave-uniform base + lane*16
__device__ __forceinline__ void gload_lds16(const unsigned short* g, unsigned short* l) {
    __builtin_amdgcn_global_load_lds(
        (__attribute__((address_space(1))) void*)g,
        (__attribute__((address_space(3))) void*)l,
        16, 0, 0);
}

// swizzled chunk index within a 128B pixel-pair window (conv layout)
__device__ __host__ __forceinline__ int swz8(int row, int i) {
    return (((row & 1) * 4 + i) ^ ((row >> 1) & 7));
}

// ---------- prep: weights into MFMA-fragment-coalesced layouts ----------
// F-layout for W[N][K]: element (o,k) -> (khg*16 + wave*4 + mt)*512 + lane*8 + j
//   wave=o>>6, mt=(o>>4)&3, l15=o&15, khg=k>>5, quad=(k>>3)&3, j=k&7, lane=quad*16+l15
// sections: W1F(327680) W2F(65536) W3F(65536) W1T(1024) W2T(9216) WfF(8192)
__global__ void prep(const float* __restrict__ f1w, const float* __restrict__ f2w,
                     const float* __restrict__ f3w, const float* __restrict__ c1w,
                     const float* __restrict__ c2w, const float* __restrict__ ffw,
                     unsigned short* __restrict__ W1F, unsigned short* __restrict__ W2F,
                     unsigned short* __restrict__ W3F, unsigned short* __restrict__ W1T,
                     unsigned short* __restrict__ W2T, unsigned short* __restrict__ WfF) {
    int i = blockIdx.x * 256 + threadIdx.x;
    if (i < 327680) {          // W1F: o in [0,256), k in [0,1280)
        int o = i / 1280, k = i - o * 1280;
        int dst = ((k >> 5) * 16 + (o >> 6) * 4 + ((o >> 4) & 3)) * 512
                + (((k >> 3) & 3) * 16 + (o & 15)) * 8 + (k & 7);
        W1F[dst] = f2b(f1w[i]);
        return;
    }
    i -= 327680;
    if (i < 65536) {           // W2F: o in [0,256), k in [0,256)
        int o = i >> 8, k = i & 255;
        int dst = ((k >> 5) * 16 + (o >> 6) * 4 + ((o >> 4) & 3)) * 512
                + (((k >> 3) & 3) * 16 + (o & 15)) * 8 + (k & 7);
        W2F[dst] = f2b(f2w[i]);
        return;
    }
    i -= 65536;
    if (i < 65536) {           // W3F
        int o = i >> 8, k = i & 255;
        int dst = ((k >> 5) * 16 + (o >> 6) * 4 + ((o >> 4) & 3)) * 512
                + (((k >> 3) & 3) * 16 + (o & 15)) * 8 + (k & 7);
        W3F[dst] = f2b(f3w[i]);
        return;
    }
    i -= 65536;
    if (i < 1024) {            // W1T[o:32][k:32], conv swizzle
        int o = i >> 5, k = i & 31;
        unsigned short v = 0;
        if (o < 20 && k < 18) v = f2b(c1w[o * 18 + k]);
        W1T[(o >> 1) * 64 + swz8(o, k >> 3) * 8 + (k & 7)] = v;
        return;
    }
    i -= 1024;
    if (i < 9216) {            // W2T[tap][o:32][c:32], conv swizzle
        int tap = i >> 10, rem = i & 1023, o = rem >> 5, c = rem & 31;
        unsigned short v = 0;
        if (o < 20 && c < 20) v = f2b(c2w[o * 180 + c * 9 + tap]);
        W2T[tap * 1024 + (o >> 1) * 64 + swz8(o, c >> 3) * 8 + (c & 7)] = v;
        return;
    }
    i -= 9216;
    if (i < 8192) {            // WfF: o in [0,32) (zero-pad >=27), k in [0,256)
        int o = i >> 8, k = i & 255;
        unsigned short v = (o < 27) ? f2b(ffw[o * 256 + k]) : (unsigned short)0;
        int dst = ((k >> 5) * 2 + (o >> 4)) * 512
                + (((k >> 3) & 3) * 16 + (o & 15)) * 8 + (k & 7);
        WfF[dst] = v;
    }
}

// ---------- fused tile + conv1(MFMA) + conv2(MFMA) (R0/R6-proven, DO NOT EDIT) ----------
// R5/R9 lessons: this structure is load-bearing — conditional window loads,
// layout changes (2080 stride / 3-store pack), and conv2 inner restructure all
// regressed despite lower VALU work. Weight LDS staging is load-bearing (R7).
__global__ __launch_bounds__(256, 3) void conv_mfma(
    const float* __restrict__ img,
    const unsigned short* __restrict__ W1T, const float* __restrict__ b1,
    const unsigned short* __restrict__ W2T, const float* __restrict__ b2,
    unsigned short* __restrict__ X, int row0)
{
    __shared__ alignas(16) unsigned short s_buf[8 * 2048 + 64];
    __shared__ alignas(16) unsigned short s_w1t[1024];
    __shared__ alignas(16) unsigned short s_w2t[9216];
    __shared__ float s_b1[32], s_b2[32];
    constexpr int ZOFF = 8 * 2048;

    const int tid = threadIdx.x;
    for (int d = tid; d < 512; d += 256)  ((unsigned int*)s_w1t)[d] = ((const unsigned int*)W1T)[d];
    for (int d = tid; d < 4608; d += 256) ((unsigned int*)s_w2t)[d] = ((const unsigned int*)W2T)[d];
    if (tid < 32) {
        ((unsigned int*)&s_buf[ZOFF])[tid] = 0u;
        s_b1[tid] = (tid < 20) ? b1[tid] : 0.f;
        s_b2[tid] = (tid < 20) ? b2[tid] : 0.f;
    }

    const int q = tid >> 5, t = tid & 31;
    const int Pl = blockIdx.x * 8 + q;
    const int Pi = row0 + Pl;
    const bool valid = Pi < NPATCH;
    int b = 0, hi = 0, wi = 0;
    if (valid) { b = Pi / 2401; int rem = Pi - b * 2401; hi = rem / 49; wi = rem - hi * 49; }
    const int py = t >> 2, px0 = (t & 3) * 2;
    const float* ib = img + (long long)b * 21632 + (hi * 2) * 104 + (wi * 2);

    float win[2][3][4];
    #pragma unroll
    for (int c = 0; c < 2; ++c)
        #pragma unroll
        for (int dy = 0; dy < 3; ++dy) {
            int ny = py + dy - 1;
            int nyc = ny < 0 ? 0 : (ny > 7 ? 7 : ny);
            #pragma unroll
            for (int dxw = 0; dxw < 4; ++dxw) {
                int nx = px0 + dxw - 1;
                int nxc = nx < 0 ? 0 : (nx > 7 ? 7 : nx);
                win[c][dy][dxw] = ib[c * 10816 + nyc * 104 + nxc];
            }
        }

    #pragma unroll
    for (int j = 0; j < 2; ++j) {
        const int px = px0 + j, pl = py * 8 + px;
        float val[18];
        #pragma unroll
        for (int c = 0; c < 2; ++c)
            #pragma unroll
            for (int dy = 0; dy < 3; ++dy) {
                int ny = py + dy - 1;
                bool rok = valid && ((unsigned)ny < 8u);
                #pragma unroll
                for (int dx = 0; dx < 3; ++dx) {
                    int nx = px + dx - 1;
                    bool ok = rok && ((unsigned)nx < 8u);
                    val[c * 9 + dy * 3 + dx] = ok ? win[c][dy][dx + j] : 0.f;
                }
            }
        alignas(16) unsigned int au[16];
        #pragma unroll
        for (int i = 0; i < 9; ++i) au[i] = pk2(val[2 * i], val[2 * i + 1]);
        #pragma unroll
        for (int i = 9; i < 16; ++i) au[i] = 0u;
        unsigned short* base = &s_buf[q * 2048 + (pl >> 1) * 64];
        #pragma unroll
        for (int i = 0; i < 4; ++i)
            *(uint4*)&base[swz8(pl, i) * 8] = ((const uint4*)au)[i];
    }
    __syncthreads();

    const int wave = tid >> 6, lane = tid & 63;
    const int l15 = lane & 15, quad = lane >> 4;
    const int p0 = wave * 2;

    int boffB[2];
    #pragma unroll
    for (int i = 0; i < 2; ++i) {
        int oo = i * 16 + l15;
        boffB[i] = (oo >> 1) * 64 + swz8(oo, quad) * 8;
    }

    short8 a1f[2];
    #pragma unroll
    for (int mt = 0; mt < 2; ++mt) a1f[mt] = *(const short8*)&s_w1t[boffB[mt]];

    floatx4 acc1[2][2][4] = {};
    #pragma unroll
    for (int pp = 0; pp < 2; ++pp)
        #pragma unroll
        for (int nt = 0; nt < 4; ++nt) {
            int pix = nt * 16 + l15;
            short8 pf = *(const short8*)&s_buf[(p0 + pp) * 2048 + (pix >> 1) * 64 + swz8(pix, quad) * 8];
            #pragma unroll
            for (int mt = 0; mt < 2; ++mt)
                acc1[pp][mt][nt] = __builtin_amdgcn_mfma_f32_16x16x32_bf16(a1f[mt], pf, acc1[pp][mt][nt], 0, 0, 0);
        }

    float bv1[2][4];
    #pragma unroll
    for (int mt = 0; mt < 2; ++mt)
        #pragma unroll
        for (int r = 0; r < 4; ++r) bv1[mt][r] = s_b1[mt * 16 + quad * 4 + r];

    #pragma unroll
    for (int pp = 0; pp < 2; ++pp)
        #pragma unroll
        for (int mt = 0; mt < 2; ++mt)
            #pragma unroll
            for (int nt = 0; nt < 4; ++nt) {
                floatx4 v = acc1[pp][mt][nt];
                uint2 w;
                w.x = pk2(fmaxf(v[0] + bv1[mt][0], 0.f), fmaxf(v[1] + bv1[mt][1], 0.f));
                w.y = pk2(fmaxf(v[2] + bv1[mt][2], 0.f), fmaxf(v[3] + bv1[mt][3], 0.f));
                int pix = nt * 16 + l15;
                int off = (p0 + pp) * 2048 + (pix >> 1) * 64
                        + swz8(pix, mt * 2 + (quad >> 1)) * 8 + (quad & 1) * 4;
                *(uint2*)&s_buf[off] = w;
            }

    int syv[4], pxv[4];
    #pragma unroll
    for (int mt = 0; mt < 4; ++mt) { int p = mt * 16 + l15; syv[mt] = p >> 3; pxv[mt] = p & 7; }

    floatx4 acc2[2][4][2] = {};
    #pragma unroll 1
    for (int dy = 0; dy < 3; ++dy) {
        int sy[4]; bool okY[4];
        #pragma unroll
        for (int mt = 0; mt < 4; ++mt) {
            sy[mt] = syv[mt] + dy - 1;
            okY[mt] = (unsigned)sy[mt] < 8u;
        }
        #pragma unroll
        for (int dx = 0; dx < 3; ++dx) {
            const int tap = dy * 3 + dx;
            short8 bf0 = *(const short8*)&s_w2t[tap * 1024 + boffB[0]];
            short8 bf1 = *(const short8*)&s_w2t[tap * 1024 + boffB[1]];
            #pragma unroll
            for (int mt = 0; mt < 4; ++mt) {
                int sx = pxv[mt] + dx - 1;
                bool ok = okY[mt] & ((unsigned)sx < 8u);
                int ps = sy[mt] * 8 + sx;
                int offl = (ps >> 1) * 64 + swz8(ps, quad) * 8;
                #pragma unroll
                for (int pp = 0; pp < 2; ++pp) {
                    int off = ok ? ((p0 + pp) * 2048 + offl) : (ZOFF + quad * 8);
                    short8 af = *(const short8*)&s_buf[off];
                    acc2[pp][mt][0] = __builtin_amdgcn_mfma_f32_16x16x32_bf16(af, bf0, acc2[pp][mt][0], 0, 0, 0);
                    acc2[pp][mt][1] = __builtin_amdgcn_mfma_f32_16x16x32_bf16(af, bf1, acc2[pp][mt][1], 0, 0, 0);
                }
            }
        }
    }

    #pragma unroll
    for (int pp = 0; pp < 2; ++pp) {
        unsigned short* xrow = X + (long long)(blockIdx.x * 8 + p0 + pp) * K1;
        #pragma unroll
        for (int nt = 0; nt < 2; ++nt) {
            const int col = nt * 16 + l15;
            if (col < 20) {
                const float bv = s_b2[col];
                #pragma unroll
                for (int mt = 0; mt < 4; ++mt) {
                    floatx4 v = acc2[pp][mt][nt];
                    uint2 w;
                    w.x = pk2(fmaxf(v[0] + bv, 0.f), fmaxf(v[1] + bv, 0.f));
                    w.y = pk2(fmaxf(v[2] + bv, 0.f), fmaxf(v[3] + bv, 0.f));
                    *(uint2*)&xrow[col * 64 + mt * 16 + quad * 4] = w;
                }
            }
        }
    }
}

// ---------- fc_all v7 (R6-proven best, ~125 µs): BK=64, af-before-stage, setprio ----------
__global__ __launch_bounds__(256, 3) void fc_all(
    const unsigned short* __restrict__ X,
    const unsigned short* __restrict__ W1F, const unsigned short* __restrict__ W2F,
    const unsigned short* __restrict__ W3F, const unsigned short* __restrict__ WfF,
    const float* __restrict__ b1, const float* __restrict__ b2,
    const float* __restrict__ b3, const float* __restrict__ bf_,
    float* __restrict__ out, int row0)
{
    __shared__ alignas(16) unsigned short s_mem[16384];   // 32 KB

    const int tid = threadIdx.x;
    const int m0 = blockIdx.x * 64;
    const int wave = tid >> 6, lane = tid & 63;
    const int l15 = lane & 15, quad = lane >> 4;

    floatx4 acc[4][4];
    #pragma unroll
    for (int mt = 0; mt < 4; ++mt)
        #pragma unroll
        for (int nt = 0; nt < 4; ++nt) acc[mt][nt] = floatx4{0.f, 0.f, 0.f, 0.f};

    // ======== fc1: K=1280 = 40 khg; chunk = 2 khg (8KB LDS), double-buffered ========
    const unsigned short* xsrc = X + (long long)(m0 + wave * 16 + l15) * 1280 + quad * 8;
    auto stage = [&](int buf, int c) {
        unsigned short* dst = &s_mem[buf * 4096 + wave * 512];
        gload_lds16(xsrc + (2 * c) * 32, dst);            // block (0*4 + wave)
        gload_lds16(xsrc + (2 * c + 1) * 32, dst + 2048); // block (1*4 + wave)
    };

    stage(0, 0);
    __syncthreads();
    #pragma unroll 2
    for (int c = 0; c < 20; ++c) {
        // 1) ALL af fragments of chunk c first (32 VGPR)
        short8 af[2][4];
        #pragma unroll
        for (int kh = 0; kh < 2; ++kh)
            #pragma unroll
            for (int mt = 0; mt < 4; ++mt)
                af[kh][mt] = *(const short8*)(W1F + (((2 * c + kh) * 16) + wave * 4 + mt) * 512 + lane * 8);
        __builtin_amdgcn_sched_barrier(0);   // pin: af loads precede the prefetch
        // 2) prefetch next X chunk (stays in flight: af waits never drain it)
        if (c < 19) stage((c + 1) & 1, c + 1);
        // 3) compute
        const int bb = (c & 1) * 4096;
        __builtin_amdgcn_s_setprio(1);
        #pragma unroll
        for (int kh = 0; kh < 2; ++kh) {
            short8 bf[4];
            #pragma unroll
            for (int nt = 0; nt < 4; ++nt)
                bf[nt] = *(const short8*)&s_mem[bb + (kh * 4 + nt) * 512 + lane * 8];
            #pragma unroll
            for (int mt = 0; mt < 4; ++mt)
                #pragma unroll
                for (int nt = 0; nt < 4; ++nt)
                    acc[mt][nt] = __builtin_amdgcn_mfma_f32_16x16x32_bf16(af[kh][mt], bf[nt], acc[mt][nt], 0, 0, 0);
        }
        __builtin_amdgcn_s_setprio(0);
        __syncthreads();   // drains prefetch (vmcnt 0) AFTER the compute phase
    }

    // h1 = relu(acc + b1) -> s_mem in fragment order (k dim = fc1 output o)
    #pragma unroll
    for (int mt = 0; mt < 4; ++mt) {
        const int obase = wave * 64 + mt * 16 + quad * 4;
        const float v0 = b1[obase], v1 = b1[obase + 1], v2 = b1[obase + 2], v3 = b1[obase + 3];
        const int slot = (wave * 2 + (mt >> 1)) * 4;          // khg*4
        const int qk = (mt & 1) * 2 + (quad >> 1);
        #pragma unroll
        for (int nt = 0; nt < 4; ++nt) {
            floatx4 v = acc[mt][nt];
            uint2 w;
            w.x = pk2(fmaxf(v[0] + v0, 0.f), fmaxf(v[1] + v1, 0.f));
            w.y = pk2(fmaxf(v[2] + v2, 0.f), fmaxf(v[3] + v3, 0.f));
            *(uint2*)&s_mem[(slot + nt) * 512 + qk * 128 + l15 * 8 + (quad & 1) * 4] = w;
        }
    }
    __syncthreads();

    // ======== fc2 / fc3: A = W F-layout (global/L2), depth-1 af pipeline ========
    #pragma unroll 1
    for (int layer = 0; layer < 2; ++layer) {
        const unsigned short* Wp = (layer == 0) ? W2F : W3F;
        const float* bp = (layer == 0) ? b2 : b3;

        #pragma unroll
        for (int mt = 0; mt < 4; ++mt)
            #pragma unroll
            for (int nt = 0; nt < 4; ++nt) acc[mt][nt] = floatx4{0.f, 0.f, 0.f, 0.f};

        short8 afc[4];
        #pragma unroll
        for (int mt = 0; mt < 4; ++mt)
            afc[mt] = *(const short8*)(Wp + (wave * 4 + mt) * 512 + lane * 8);

        #pragma unroll
        for (int it = 0; it < 8; ++it) {
            short8 afn[4];
            if (it < 7) {
                #pragma unroll
                for (int mt = 0; mt < 4; ++mt)
                    afn[mt] = *(const short8*)(Wp + ((it + 1) * 16 + wave * 4 + mt) * 512 + lane * 8);
            }
            short8 bf[4];
            #pragma unroll
            for (int nt = 0; nt < 4; ++nt)
                bf[nt] = *(const short8*)&s_mem[(it * 4 + nt) * 512 + lane * 8];
            __builtin_amdgcn_s_setprio(1);
            #pragma unroll
            for (int mt = 0; mt < 4; ++mt)
                #pragma unroll
                for (int nt = 0; nt < 4; ++nt)
                    acc[mt][nt] = __builtin_amdgcn_mfma_f32_16x16x32_bf16(afc[mt], bf[nt], acc[mt][nt], 0, 0, 0);
            __builtin_amdgcn_s_setprio(0);
            if (it < 7) {
                #pragma unroll
                for (int mt = 0; mt < 4; ++mt) afc[mt] = afn[mt];
            }
        }
        __syncthreads();   // all reads of h done before overwrite
        #pragma unroll
        for (int mt = 0; mt < 4; ++mt) {
            const int obase = wave * 64 + mt * 16 + quad * 4;
            const float v0 = bp[obase], v1 = bp[obase + 1], v2 = bp[obase + 2], v3 = bp[obase + 3];
            const int slot = (wave * 2 + (mt >> 1)) * 4;
            const int qk = (mt & 1) * 2 + (quad >> 1);
            #pragma unroll
            for (int nt = 0; nt < 4; ++nt) {
                floatx4 v = acc[mt][nt];
                uint2 w;
                w.x = pk2(fmaxf(v[0] + v0, 0.f), fmaxf(v[1] + v1, 0.f));
                w.y = pk2(fmaxf(v[2] + v2, 0.f), fmaxf(v[3] + v3, 0.f));
                *(uint2*)&s_mem[(slot + nt) * 512 + qk * 128 + l15 * 8 + (quad & 1) * 4] = w;
            }
        }
        __syncthreads();
    }

    // ======== fcf: A = WfF (global, coalesced), B = h3 fragments ========
    floatx4 accf[2] = {floatx4{0.f, 0.f, 0.f, 0.f}, floatx4{0.f, 0.f, 0.f, 0.f}};
    const int myrow = wave * 16 + l15;
    #pragma unroll
    for (int w8 = 0; w8 < 8; ++w8) {
        short8 bfr = *(const short8*)&s_mem[(w8 * 4 + wave) * 512 + lane * 8];
        #pragma unroll
        for (int mt = 0; mt < 2; ++mt) {
            short8 afr = *(const short8*)(WfF + (w8 * 2 + mt) * 512 + lane * 8);
            accf[mt] = __builtin_amdgcn_mfma_f32_16x16x32_bf16(afr, bfr, accf[mt], 0, 0, 0);
        }
    }
    const int grow = row0 + m0 + myrow;
    if (grow < NPATCH) {
        #pragma unroll
        for (int mt = 0; mt < 2; ++mt) {
            #pragma unroll
            for (int r = 0; r < 4; ++r) {
                int o = mt * 16 + quad * 4 + r;
                if (o < 27)
                    out[(long long)grow * 27 + o] = accf[mt][r] + bf_[o];
            }
        }
    }
}

extern "C" void kernel_launch(void* const* d_in, const int* in_sizes, int n_in,
                              void* d_out, int out_size, void* d_ws, size_t ws_size,
                              hipStream_t stream) {
    const float* images = (const float*)d_in[0];
    const float* c1w = (const float*)d_in[1];
    const float* c1b = (const float*)d_in[2];
    const float* c2w = (const float*)d_in[3];
    const float* c2b = (const float*)d_in[4];
    const float* f1w = (const float*)d_in[5];
    const float* f1b = (const float*)d_in[6];
    const float* f2w = (const float*)d_in[7];
    const float* f2b_ = (const float*)d_in[8];
    const float* f3w = (const float*)d_in[9];
    const float* f3b = (const float*)d_in[10];
    const float* ffw = (const float*)d_in[11];
    const float* ffb = (const float*)d_in[12];

    // ws: [W1F][W2F][W3F][W1T][W2T][WfF][X]
    const long long W1_E = 327680, W2_E = 65536, W3_E = 65536;
    const long long W1T_E = 1024, W2T_E = 9216, WF_E = 8192;
    const long long WB = (W1_E + W2_E + W3_E + W1T_E + W2T_E + WF_E) * 2;  // 954368
    char* ws = (char*)d_ws;
    unsigned short* W1F = (unsigned short*)ws;
    unsigned short* W2F = W1F + W1_E;
    unsigned short* W3F = W2F + W2_E;
    unsigned short* W1T = W3F + W3_E;
    unsigned short* W2T = W1T + W1T_E;
    unsigned short* WfF = W2T + W2T_E;
    unsigned short* X   = (unsigned short*)(ws + WB);

    prep<<<1864, 256, 0, stream>>>(f1w, f2w, f3w, c1w, c2w, ffw, W1F, W2F, W3F, W1T, W2T, WfF);

    // MEASUREMENT ROUND: split ONLY conv into two half-grid dispatches so fc_all
    // (single 1201-block dispatch, ~125 µs) becomes the longest dispatch class
    // and finally shows up in the rocprof top-5 with full PMC. fc reads X
    // absolutely (row0 = 0); each conv launch writes at X + row0*K1 since its
    // blockIdx is launch-relative. Expected cost vs R6 best: ~+12 µs (conv
    // split tails), knowingly paid for fc's counters.
    {
        const int half = (NBLK + 1) / 2;          // 301 blocks of 128 rows
        const int rows0 = half * 128;             // 38528
        const int rows1 = NBLK * 128 - rows0;     // 38400
        conv_mfma<<<rows0 / 8, 256, 0, stream>>>(images, W1T, c1b, W2T, c2b,
                                                 X, 0);
        conv_mfma<<<rows1 / 8, 256, 0, stream>>>(images, W1T, c1b, W2T, c2b,
                                                 X + (long long)rows0 * K1, rows0);
        fc_all<<<(NBLK * 128) / 64, 256, 0, stream>>>(X, W1F, W2F, W3F, WfF,
                                                      f1b, f2b_, f3b, ffb,
                                                      (float*)d_out, 0);
    }
}

// Round 14
// 293.375 us; speedup vs baseline: 1.1061x; 1.0366x over previous
//
#include <hip/hip_runtime.h>
#include <hip/hip_bf16.h>

// ---------- constants ----------
#define NPATCH 76832   // 32 * 49 * 49
#define NBLK   601     // ceil(NPATCH/128)
#define K1     1280    // 20*8*8

typedef __attribute__((ext_vector_type(8))) short  short8;
typedef __attribute__((ext_vector_type(4))) float  floatx4;

__device__ __forceinline__ unsigned short f2b(float f) {
    unsigned int u = __builtin_bit_cast(unsigned int, f);
    u += 0x7FFFu + ((u >> 16) & 1u);   // RNE
    return (unsigned short)(u >> 16);
}
// HW packed f32x2 -> bf16x2 (v_cvt_pk_bf16_f32), a -> low
__device__ __forceinline__ unsigned int pk2(float a, float b) {
    __hip_bfloat162 h = __float22bfloat162_rn(make_float2(a, b));
    unsigned int u;
    __builtin_memcpy(&u, &h, 4);
    return u;
}

// async global->LDS, 16B/lane; global addr PER-LANE, lds dest = wave-uniform base + lane*16
__device__ __forceinline__ void gload_lds16(const unsigned short* g, unsigned short* l) {
    __builtin_amdgcn_global_load_lds(
        (__attribute__((address_space(1))) void*)g,
        (__attribute__((address_space(3))) void*)l,
        16, 0, 0);
}

// swizzled chunk index within a 128B pixel-pair window (conv layout)
__device__ __host__ __forceinline__ int swz8(int row, int i) {
    return (((row & 1) * 4 + i) ^ ((row >> 1) & 7));
}

// ---------- prep_small: conv weights only (W1T/W2T), 40 blocks, ~2 µs ----------
// The heavy fc-weight prep (W1F/W2F/W3F/WfF) is embedded in conv_mfma's tail
// (rides in conv's stall slack; conv precedes fc on the stream).
__global__ void prep_small(const float* __restrict__ c1w, const float* __restrict__ c2w,
                           unsigned short* __restrict__ W1T, unsigned short* __restrict__ W2T) {
    int i = blockIdx.x * 256 + threadIdx.x;
    if (i < 1024) {            // W1T[o:32][k:32], conv swizzle
        int o = i >> 5, k = i & 31;
        unsigned short v = 0;
        if (o < 20 && k < 18) v = f2b(c1w[o * 18 + k]);
        W1T[(o >> 1) * 64 + swz8(o, k >> 3) * 8 + (k & 7)] = v;
        return;
    }
    i -= 1024;
    if (i < 9216) {            // W2T[tap][o:32][c:32], conv swizzle
        int tap = i >> 10, rem = i & 1023, o = rem >> 5, c = rem & 31;
        unsigned short v = 0;
        if (o < 20 && c < 20) v = f2b(c2w[o * 180 + c * 9 + tap]);
        W2T[tap * 1024 + (o >> 1) * 64 + swz8(o, c >> 3) * 8 + (c & 7)] = v;
    }
}

// ---------- fused tile + conv1(MFMA) + conv2(MFMA) (R0/R6-proven hot path, DO NOT EDIT)
// + embedded fc-weight prep tail (guarded, uniform branch, after the epilogue).
// R5/R9 lessons: the hot-path structure is load-bearing — conditional window
// loads, layout changes, conv2 inner restructure all regressed. Weight LDS
// staging is load-bearing (R7).
// F-layout for W[N][K]: element (o,k) -> ((k>>5)*16 + (o>>6)*4 + ((o>>4)&3))*512
//                                       + (((k>>3)&3)*16 + (o&15))*8 + (k&7)
__global__ __launch_bounds__(256, 3) void conv_mfma(
    const float* __restrict__ img,
    const unsigned short* __restrict__ W1T, const float* __restrict__ b1,
    const unsigned short* __restrict__ W2T, const float* __restrict__ b2,
    unsigned short* __restrict__ X, int row0,
    const float* __restrict__ f1w, const float* __restrict__ f2w,
    const float* __restrict__ f3w, const float* __restrict__ ffw,
    unsigned short* __restrict__ W1F, unsigned short* __restrict__ W2F,
    unsigned short* __restrict__ W3F, unsigned short* __restrict__ WfF)
{
    __shared__ alignas(16) unsigned short s_buf[8 * 2048 + 64];
    __shared__ alignas(16) unsigned short s_w1t[1024];
    __shared__ alignas(16) unsigned short s_w2t[9216];
    __shared__ float s_b1[32], s_b2[32];
    constexpr int ZOFF = 8 * 2048;

    const int tid = threadIdx.x;
    for (int d = tid; d < 512; d += 256)  ((unsigned int*)s_w1t)[d] = ((const unsigned int*)W1T)[d];
    for (int d = tid; d < 4608; d += 256) ((unsigned int*)s_w2t)[d] = ((const unsigned int*)W2T)[d];
    if (tid < 32) {
        ((unsigned int*)&s_buf[ZOFF])[tid] = 0u;
        s_b1[tid] = (tid < 20) ? b1[tid] : 0.f;
        s_b2[tid] = (tid < 20) ? b2[tid] : 0.f;
    }

    const int q = tid >> 5, t = tid & 31;
    const int Pl = blockIdx.x * 8 + q;
    const int Pi = row0 + Pl;
    const bool valid = Pi < NPATCH;
    int b = 0, hi = 0, wi = 0;
    if (valid) { b = Pi / 2401; int rem = Pi - b * 2401; hi = rem / 49; wi = rem - hi * 49; }
    const int py = t >> 2, px0 = (t & 3) * 2;
    const float* ib = img + (long long)b * 21632 + (hi * 2) * 104 + (wi * 2);

    float win[2][3][4];
    #pragma unroll
    for (int c = 0; c < 2; ++c)
        #pragma unroll
        for (int dy = 0; dy < 3; ++dy) {
            int ny = py + dy - 1;
            int nyc = ny < 0 ? 0 : (ny > 7 ? 7 : ny);
            #pragma unroll
            for (int dxw = 0; dxw < 4; ++dxw) {
                int nx = px0 + dxw - 1;
                int nxc = nx < 0 ? 0 : (nx > 7 ? 7 : nx);
                win[c][dy][dxw] = ib[c * 10816 + nyc * 104 + nxc];
            }
        }

    #pragma unroll
    for (int j = 0; j < 2; ++j) {
        const int px = px0 + j, pl = py * 8 + px;
        float val[18];
        #pragma unroll
        for (int c = 0; c < 2; ++c)
            #pragma unroll
            for (int dy = 0; dy < 3; ++dy) {
                int ny = py + dy - 1;
                bool rok = valid && ((unsigned)ny < 8u);
                #pragma unroll
                for (int dx = 0; dx < 3; ++dx) {
                    int nx = px + dx - 1;
                    bool ok = rok && ((unsigned)nx < 8u);
                    val[c * 9 + dy * 3 + dx] = ok ? win[c][dy][dx + j] : 0.f;
                }
            }
        alignas(16) unsigned int au[16];
        #pragma unroll
        for (int i = 0; i < 9; ++i) au[i] = pk2(val[2 * i], val[2 * i + 1]);
        #pragma unroll
        for (int i = 9; i < 16; ++i) au[i] = 0u;
        unsigned short* base = &s_buf[q * 2048 + (pl >> 1) * 64];
        #pragma unroll
        for (int i = 0; i < 4; ++i)
            *(uint4*)&base[swz8(pl, i) * 8] = ((const uint4*)au)[i];
    }
    __syncthreads();

    const int wave = tid >> 6, lane = tid & 63;
    const int l15 = lane & 15, quad = lane >> 4;
    const int p0 = wave * 2;

    int boffB[2];
    #pragma unroll
    for (int i = 0; i < 2; ++i) {
        int oo = i * 16 + l15;
        boffB[i] = (oo >> 1) * 64 + swz8(oo, quad) * 8;
    }

    short8 a1f[2];
    #pragma unroll
    for (int mt = 0; mt < 2; ++mt) a1f[mt] = *(const short8*)&s_w1t[boffB[mt]];

    floatx4 acc1[2][2][4] = {};
    #pragma unroll
    for (int pp = 0; pp < 2; ++pp)
        #pragma unroll
        for (int nt = 0; nt < 4; ++nt) {
            int pix = nt * 16 + l15;
            short8 pf = *(const short8*)&s_buf[(p0 + pp) * 2048 + (pix >> 1) * 64 + swz8(pix, quad) * 8];
            #pragma unroll
            for (int mt = 0; mt < 2; ++mt)
                acc1[pp][mt][nt] = __builtin_amdgcn_mfma_f32_16x16x32_bf16(a1f[mt], pf, acc1[pp][mt][nt], 0, 0, 0);
        }

    float bv1[2][4];
    #pragma unroll
    for (int mt = 0; mt < 2; ++mt)
        #pragma unroll
        for (int r = 0; r < 4; ++r) bv1[mt][r] = s_b1[mt * 16 + quad * 4 + r];

    #pragma unroll
    for (int pp = 0; pp < 2; ++pp)
        #pragma unroll
        for (int mt = 0; mt < 2; ++mt)
            #pragma unroll
            for (int nt = 0; nt < 4; ++nt) {
                floatx4 v = acc1[pp][mt][nt];
                uint2 w;
                w.x = pk2(fmaxf(v[0] + bv1[mt][0], 0.f), fmaxf(v[1] + bv1[mt][1], 0.f));
                w.y = pk2(fmaxf(v[2] + bv1[mt][2], 0.f), fmaxf(v[3] + bv1[mt][3], 0.f));
                int pix = nt * 16 + l15;
                int off = (p0 + pp) * 2048 + (pix >> 1) * 64
                        + swz8(pix, mt * 2 + (quad >> 1)) * 8 + (quad & 1) * 4;
                *(uint2*)&s_buf[off] = w;
            }

    int syv[4], pxv[4];
    #pragma unroll
    for (int mt = 0; mt < 4; ++mt) { int p = mt * 16 + l15; syv[mt] = p >> 3; pxv[mt] = p & 7; }

    floatx4 acc2[2][4][2] = {};
    #pragma unroll 1
    for (int dy = 0; dy < 3; ++dy) {
        int sy[4]; bool okY[4];
        #pragma unroll
        for (int mt = 0; mt < 4; ++mt) {
            sy[mt] = syv[mt] + dy - 1;
            okY[mt] = (unsigned)sy[mt] < 8u;
        }
        #pragma unroll
        for (int dx = 0; dx < 3; ++dx) {
            const int tap = dy * 3 + dx;
            short8 bf0 = *(const short8*)&s_w2t[tap * 1024 + boffB[0]];
            short8 bf1 = *(const short8*)&s_w2t[tap * 1024 + boffB[1]];
            #pragma unroll
            for (int mt = 0; mt < 4; ++mt) {
                int sx = pxv[mt] + dx - 1;
                bool ok = okY[mt] & ((unsigned)sx < 8u);
                int ps = sy[mt] * 8 + sx;
                int offl = (ps >> 1) * 64 + swz8(ps, quad) * 8;
                #pragma unroll
                for (int pp = 0; pp < 2; ++pp) {
                    int off = ok ? ((p0 + pp) * 2048 + offl) : (ZOFF + quad * 8);
                    short8 af = *(const short8*)&s_buf[off];
                    acc2[pp][mt][0] = __builtin_amdgcn_mfma_f32_16x16x32_bf16(af, bf0, acc2[pp][mt][0], 0, 0, 0);
                    acc2[pp][mt][1] = __builtin_amdgcn_mfma_f32_16x16x32_bf16(af, bf1, acc2[pp][mt][1], 0, 0, 0);
                }
            }
        }
    }

    #pragma unroll
    for (int pp = 0; pp < 2; ++pp) {
        unsigned short* xrow = X + (long long)(blockIdx.x * 8 + p0 + pp) * K1;
        #pragma unroll
        for (int nt = 0; nt < 2; ++nt) {
            const int col = nt * 16 + l15;
            if (col < 20) {
                const float bv = s_b2[col];
                #pragma unroll
                for (int mt = 0; mt < 4; ++mt) {
                    floatx4 v = acc2[pp][mt][nt];
                    uint2 w;
                    w.x = pk2(fmaxf(v[0] + bv, 0.f), fmaxf(v[1] + bv, 0.f));
                    w.y = pk2(fmaxf(v[2] + bv, 0.f), fmaxf(v[3] + bv, 0.f));
                    *(uint2*)&xrow[col * 64 + mt * 16 + quad * 4] = w;
                }
            }
        }
    }

    // ---- embedded fc-weight prep tail (first 800 blocks of chunk 0 only) ----
    // Coalesced reads (block = o-row, threads = k), no integer divide.
    // Completes before fc_all launches (same stream). Hidden in conv's slack.
    if (row0 == 0 && blockIdx.x < 800) {
        const int bb_ = blockIdx.x;
        if (bb_ < 256) {               // W1F: o = bb_, k = tid + 256*j (5 elems)
            const int o = bb_;
            const int obase = ((o >> 6) * 4 + ((o >> 4) & 3)) * 512 + (o & 15) * 8;
            #pragma unroll
            for (int j = 0; j < 5; ++j) {
                int k = tid + 256 * j;
                int dst = (k >> 5) * 8192 + obase + ((k >> 3) & 3) * 128 + (k & 7);
                W1F[dst] = f2b(f1w[o * 1280 + k]);
            }
        } else if (bb_ < 512) {        // W2F: o = bb_-256, k = tid
            const int o = bb_ - 256, k = tid;
            int dst = ((k >> 5) * 16 + (o >> 6) * 4 + ((o >> 4) & 3)) * 512
                    + (((k >> 3) & 3) * 16 + (o & 15)) * 8 + (k & 7);
            W2F[dst] = f2b(f2w[o * 256 + k]);
        } else if (bb_ < 768) {        // W3F: o = bb_-512, k = tid
            const int o = bb_ - 512, k = tid;
            int dst = ((k >> 5) * 16 + (o >> 6) * 4 + ((o >> 4) & 3)) * 512
                    + (((k >> 3) & 3) * 16 + (o & 15)) * 8 + (k & 7);
            W3F[dst] = f2b(f3w[o * 256 + k]);
        } else {                       // WfF: o = bb_-768 (<32, zero-pad >=27), k = tid
            const int o = bb_ - 768, k = tid;
            unsigned short v = (o < 27) ? f2b(ffw[o * 256 + k]) : (unsigned short)0;
            int dst = ((k >> 5) * 2 + (o >> 4)) * 512
                    + (((k >> 3) & 3) * 16 + (o & 15)) * 8 + (k & 7);
            WfF[dst] = v;
        }
    }
}

// ---------- fc_all v7 (proven, 86 µs measured R13): BK=64, af-before-stage, setprio ----------
__global__ __launch_bounds__(256, 3) void fc_all(
    const unsigned short* __restrict__ X,
    const unsigned short* __restrict__ W1F, const unsigned short* __restrict__ W2F,
    const unsigned short* __restrict__ W3F, const unsigned short* __restrict__ WfF,
    const float* __restrict__ b1, const float* __restrict__ b2,
    const float* __restrict__ b3, const float* __restrict__ bf_,
    float* __restrict__ out, int row0)
{
    __shared__ alignas(16) unsigned short s_mem[16384];   // 32 KB

    const int tid = threadIdx.x;
    const int m0 = blockIdx.x * 64;
    const int wave = tid >> 6, lane = tid & 63;
    const int l15 = lane & 15, quad = lane >> 4;

    floatx4 acc[4][4];
    #pragma unroll
    for (int mt = 0; mt < 4; ++mt)
        #pragma unroll
        for (int nt = 0; nt < 4; ++nt) acc[mt][nt] = floatx4{0.f, 0.f, 0.f, 0.f};

    // ======== fc1: K=1280 = 40 khg; chunk = 2 khg (8KB LDS), double-buffered ========
    const unsigned short* xsrc = X + (long long)(m0 + wave * 16 + l15) * 1280 + quad * 8;
    auto stage = [&](int buf, int c) {
        unsigned short* dst = &s_mem[buf * 4096 + wave * 512];
        gload_lds16(xsrc + (2 * c) * 32, dst);            // block (0*4 + wave)
        gload_lds16(xsrc + (2 * c + 1) * 32, dst + 2048); // block (1*4 + wave)
    };

    stage(0, 0);
    __syncthreads();
    #pragma unroll 2
    for (int c = 0; c < 20; ++c) {
        // 1) ALL af fragments of chunk c first (32 VGPR)
        short8 af[2][4];
        #pragma unroll
        for (int kh = 0; kh < 2; ++kh)
            #pragma unroll
            for (int mt = 0; mt < 4; ++mt)
                af[kh][mt] = *(const short8*)(W1F + (((2 * c + kh) * 16) + wave * 4 + mt) * 512 + lane * 8);
        __builtin_amdgcn_sched_barrier(0);   // pin: af loads precede the prefetch
        // 2) prefetch next X chunk (stays in flight: af waits never drain it)
        if (c < 19) stage((c + 1) & 1, c + 1);
        // 3) compute
        const int bb = (c & 1) * 4096;
        __builtin_amdgcn_s_setprio(1);
        #pragma unroll
        for (int kh = 0; kh < 2; ++kh) {
            short8 bf[4];
            #pragma unroll
            for (int nt = 0; nt < 4; ++nt)
                bf[nt] = *(const short8*)&s_mem[bb + (kh * 4 + nt) * 512 + lane * 8];
            #pragma unroll
            for (int mt = 0; mt < 4; ++mt)
                #pragma unroll
                for (int nt = 0; nt < 4; ++nt)
                    acc[mt][nt] = __builtin_amdgcn_mfma_f32_16x16x32_bf16(af[kh][mt], bf[nt], acc[mt][nt], 0, 0, 0);
        }
        __builtin_amdgcn_s_setprio(0);
        __syncthreads();   // drains prefetch (vmcnt 0) AFTER the compute phase
    }

    // h1 = relu(acc + b1) -> s_mem in fragment order (k dim = fc1 output o)
    #pragma unroll
    for (int mt = 0; mt < 4; ++mt) {
        const int obase = wave * 64 + mt * 16 + quad * 4;
        const float v0 = b1[obase], v1 = b1[obase + 1], v2 = b1[obase + 2], v3 = b1[obase + 3];
        const int slot = (wave * 2 + (mt >> 1)) * 4;          // khg*4
        const int qk = (mt & 1) * 2 + (quad >> 1);
        #pragma unroll
        for (int nt = 0; nt < 4; ++nt) {
            floatx4 v = acc[mt][nt];
            uint2 w;
            w.x = pk2(fmaxf(v[0] + v0, 0.f), fmaxf(v[1] + v1, 0.f));
            w.y = pk2(fmaxf(v[2] + v2, 0.f), fmaxf(v[3] + v3, 0.f));
            *(uint2*)&s_mem[(slot + nt) * 512 + qk * 128 + l15 * 8 + (quad & 1) * 4] = w;
        }
    }
    __syncthreads();

    // ======== fc2 / fc3: A = W F-layout (global/L2), depth-1 af pipeline ========
    #pragma unroll 1
    for (int layer = 0; layer < 2; ++layer) {
        const unsigned short* Wp = (layer == 0) ? W2F : W3F;
        const float* bp = (layer == 0) ? b2 : b3;

        #pragma unroll
        for (int mt = 0; mt < 4; ++mt)
            #pragma unroll
            for (int nt = 0; nt < 4; ++nt) acc[mt][nt] = floatx4{0.f, 0.f, 0.f, 0.f};

        short8 afc[4];
        #pragma unroll
        for (int mt = 0; mt < 4; ++mt)
            afc[mt] = *(const short8*)(Wp + (wave * 4 + mt) * 512 + lane * 8);

        #pragma unroll
        for (int it = 0; it < 8; ++it) {
            short8 afn[4];
            if (it < 7) {
                #pragma unroll
                for (int mt = 0; mt < 4; ++mt)
                    afn[mt] = *(const short8*)(Wp + ((it + 1) * 16 + wave * 4 + mt) * 512 + lane * 8);
            }
            short8 bf[4];
            #pragma unroll
            for (int nt = 0; nt < 4; ++nt)
                bf[nt] = *(const short8*)&s_mem[(it * 4 + nt) * 512 + lane * 8];
            __builtin_amdgcn_s_setprio(1);
            #pragma unroll
            for (int mt = 0; mt < 4; ++mt)
                #pragma unroll
                for (int nt = 0; nt < 4; ++nt)
                    acc[mt][nt] = __builtin_amdgcn_mfma_f32_16x16x32_bf16(afc[mt], bf[nt], acc[mt][nt], 0, 0, 0);
            __builtin_amdgcn_s_setprio(0);
            if (it < 7) {
                #pragma unroll
                for (int mt = 0; mt < 4; ++mt) afc[mt] = afn[mt];
            }
        }
        __syncthreads();   // all reads of h done before overwrite
        #pragma unroll
        for (int mt = 0; mt < 4; ++mt) {
            const int obase = wave * 64 + mt * 16 + quad * 4;
            const float v0 = bp[obase], v1 = bp[obase + 1], v2 = bp[obase + 2], v3 = bp[obase + 3];
            const int slot = (wave * 2 + (mt >> 1)) * 4;
            const int qk = (mt & 1) * 2 + (quad >> 1);
            #pragma unroll
            for (int nt = 0; nt < 4; ++nt) {
                floatx4 v = acc[mt][nt];
                uint2 w;
                w.x = pk2(fmaxf(v[0] + v0, 0.f), fmaxf(v[1] + v1, 0.f));
                w.y = pk2(fmaxf(v[2] + v2, 0.f), fmaxf(v[3] + v3, 0.f));
                *(uint2*)&s_mem[(slot + nt) * 512 + qk * 128 + l15 * 8 + (quad & 1) * 4] = w;
            }
        }
        __syncthreads();
    }

    // ======== fcf: A = WfF (global, coalesced), B = h3 fragments ========
    floatx4 accf[2] = {floatx4{0.f, 0.f, 0.f, 0.f}, floatx4{0.f, 0.f, 0.f, 0.f}};
    const int myrow = wave * 16 + l15;
    #pragma unroll
    for (int w8 = 0; w8 < 8; ++w8) {
        short8 bfr = *(const short8*)&s_mem[(w8 * 4 + wave) * 512 + lane * 8];
        #pragma unroll
        for (int mt = 0; mt < 2; ++mt) {
            short8 afr = *(const short8*)(WfF + (w8 * 2 + mt) * 512 + lane * 8);
            accf[mt] = __builtin_amdgcn_mfma_f32_16x16x32_bf16(afr, bfr, accf[mt], 0, 0, 0);
        }
    }
    const int grow = row0 + m0 + myrow;
    if (grow < NPATCH) {
        #pragma unroll
        for (int mt = 0; mt < 2; ++mt) {
            #pragma unroll
            for (int r = 0; r < 4; ++r) {
                int o = mt * 16 + quad * 4 + r;
                if (o < 27)
                    out[(long long)grow * 27 + o] = accf[mt][r] + bf_[o];
            }
        }
    }
}

extern "C" void kernel_launch(void* const* d_in, const int* in_sizes, int n_in,
                              void* d_out, int out_size, void* d_ws, size_t ws_size,
                              hipStream_t stream) {
    const float* images = (const float*)d_in[0];
    const float* c1w = (const float*)d_in[1];
    const float* c1b = (const float*)d_in[2];
    const float* c2w = (const float*)d_in[3];
    const float* c2b = (const float*)d_in[4];
    const float* f1w = (const float*)d_in[5];
    const float* f1b = (const float*)d_in[6];
    const float* f2w = (const float*)d_in[7];
    const float* f2b_ = (const float*)d_in[8];
    const float* f3w = (const float*)d_in[9];
    const float* f3b = (const float*)d_in[10];
    const float* ffw = (const float*)d_in[11];
    const float* ffb = (const float*)d_in[12];

    // ws: [W1F][W2F][W3F][W1T][W2T][WfF][X]
    const long long W1_E = 327680, W2_E = 65536, W3_E = 65536;
    const long long W1T_E = 1024, W2T_E = 9216, WF_E = 8192;
    const long long WB = (W1_E + W2_E + W3_E + W1T_E + W2T_E + WF_E) * 2;  // 954368
    char* ws = (char*)d_ws;
    unsigned short* W1F = (unsigned short*)ws;
    unsigned short* W2F = W1F + W1_E;
    unsigned short* W3F = W2F + W2_E;
    unsigned short* W1T = W3F + W3_E;
    unsigned short* W2T = W1T + W1T_E;
    unsigned short* WfF = W2T + W2T_E;
    unsigned short* X   = (unsigned short*)(ws + WB);

    // per 128-row block: X only = 327680 B
    long long avail = (long long)ws_size - WB - 256;
    int nb_max = (int)(avail / 327680LL);
    if (nb_max < 1) nb_max = 1;
    if (nb_max > NBLK) nb_max = NBLK;
    int nchunks = (NBLK + nb_max - 1) / nb_max;
    int nb_even = (NBLK + nchunks - 1) / nchunks;

    // tiny prep: conv weights only (~2 µs). fc weights are produced by
    // conv_mfma's embedded tail (chunk 0), which completes before fc_all runs.
    prep_small<<<40, 256, 0, stream>>>(c1w, c2w, W1T, W2T);

    for (int b0 = 0; b0 < NBLK; b0 += nb_even) {
        int nb = NBLK - b0; if (nb > nb_even) nb = nb_even;
        int row0 = b0 * 128;
        int rows = nb * 128;

        conv_mfma<<<rows / 8, 256, 0, stream>>>(images, W1T, c1b, W2T, c2b, X, row0,
                                                f1w, f2w, f3w, ffw, W1F, W2F, W3F, WfF);
        fc_all<<<rows / 64, 256, 0, stream>>>(X, W1F, W2F, W3F, WfF,
                                              f1b, f2b_, f3b, ffb, (float*)d_out, row0);
    }
}